// Round 3
// 5777.361 us; speedup vs baseline: 2.8608x; 2.8608x over previous
//
#include <hip/hip_runtime.h>

typedef float v2f __attribute__((ext_vector_type(2)));

#define HH 1024
#define BB 128
#define TT 400
#define SS 64
#define CC 8

constexpr int   N_EXC     = 819;          // int(1024*0.8)
constexpr float DT_SEC    = 0.02f;
constexpr float ALPHA_N   = 0.2f;         // DT/TAU_N
constexpr float NOISE_STD = 0.05f;

// ---------------- K2: feed-forward drive into acts region [B][T][H] ----
#define TCH 16
__global__ void drive_kernel(const float* __restrict__ stim, const float* __restrict__ ctx,
                             const float* __restrict__ w_in, const float* __restrict__ w_ctx,
                             float* __restrict__ drive) {
    int b  = blockIdx.x / (TT / TCH);
    int tc = blockIdx.x % (TT / TCH);
    int t0 = tc * TCH;
    __shared__ float sbuf[TCH][SS + CC];
    int tid = threadIdx.x;
    for (int idx = tid; idx < TCH * SS; idx += 256) {
        int k = idx >> 6, s2 = idx & 63;
        sbuf[k][s2] = stim[((size_t)b * TT + t0 + k) * SS + s2];
    }
    for (int idx = tid; idx < TCH * CC; idx += 256) {
        int k = idx >> 3, c2 = idx & 7;
        sbuf[k][SS + c2] = ctx[((size_t)b * TT + t0 + k) * CC + c2];
    }
    __syncthreads();
    for (int h = tid; h < HH; h += 256) {
        float acc[TCH];
        #pragma unroll
        for (int k = 0; k < TCH; ++k) acc[k] = 0.0f;
        const float4* wr = (const float4*)(w_in + (size_t)h * SS);
        #pragma unroll
        for (int s4 = 0; s4 < SS / 4; ++s4) {
            float4 w = wr[s4];
            #pragma unroll
            for (int k = 0; k < TCH; ++k) {
                float4 a = *(const float4*)(&sbuf[k][s4 * 4]);
                acc[k] += w.x * a.x + w.y * a.y + w.z * a.z + w.w * a.w;
            }
        }
        const float4* wc = (const float4*)(w_ctx + (size_t)h * CC);
        #pragma unroll
        for (int c4 = 0; c4 < CC / 4; ++c4) {
            float4 w = wc[c4];
            #pragma unroll
            for (int k = 0; k < TCH; ++k) {
                float4 a = *(const float4*)(&sbuf[k][SS + c4 * 4]);
                acc[k] += w.x * a.x + w.y * a.y + w.z * a.z + w.w * a.w;
            }
        }
        #pragma unroll
        for (int k = 0; k < TCH; ++k)
            drive[((size_t)b * TT + t0 + k) * HH + h] = acc[k];
    }
}

// ---------------- K3: one kernel PER TIMESTEP ---------------------------
// Sync retreat (R1/R2 post-mortem): the hand-rolled cross-XCD flag barrier
// failed twice with the documented wbl2/inv release-acquire sequence; kernel
// dispatch boundaries are the only HW-validated device-wide coherence here.
// 400 sequential launches on one stream (graph-captured). Each K_t:
//   reads  h_post(t)  from hp_buf[par=t&1]   (written by K_{t-1}; t=0 -> zero)
//   reads  h(t-1)     from acts[b][t-1]      (written by K_{t-1}; t=0 -> 0)
//   reads  sx(t),su(t) from scratch          (written by K_{t-1}; t=0 -> 1,U)
//   computes h(t) = relu(...matvec(h_post(t))...), writes acts[b][t]
//   STP-updates to sx(t+1),su(t+1), writes them + h_post(t+1) to hp[parw].
// Recurrence mapping verified against the reference scan incl. t=0 boundary:
// reference step t computes sx'(t),su'(t) from h_{t-1} FIRST, so K_{t-1}
// (which holds h_{t-1}) performs that update and K_t consumes it ready-made.
// Inner staging/FMA/reduce p-loop is VERBATIM the round-0 passing kernel
// (identical numerics; acts round-trip is exact fp32).
// Block/thread decomposition unchanged: 256 blocks = 32 j-tiles x 8
// batch-tiles; compute role (jg,ig) holds W[ig*32..+32][jb*32+jg*4..+4] in
// 128 VGPRs (reloaded each step from L2: W is 4 MB, L2-resident).
__global__ void __launch_bounds__(256, 1)
step_kernel(const float* __restrict__ w_rec, const float* __restrict__ noise,
            const float* __restrict__ b_rec, float* acts_drive,
            float* __restrict__ hp_buf, float* __restrict__ sxg,
            float* __restrict__ sug, int t) {
    const int bid = blockIdx.x;
    const int jb  = bid & 31;            // 32 j-tiles
    const int bb  = bid >> 5;            // 8 batch-tiles of 16
    const int tid = threadIdx.x;

    const int jg = tid & 7;              // compute: 8 groups x 4 j-cols
    const int ig = tid >> 3;             // compute: 32 groups x 32 i-rows
    const int jj = tid & 31;             // state: column
    const int sb = tid >> 5;             // state: batch-in-pass (0..7)
    const int j  = jb * 32 + jj;

    __shared__ float hp_lds[8 * HH];     // 32 KB (reused by both passes)
    __shared__ float part[32 * 8 * 32];  // 32 KB [ig][b][skewed slot]

    // ---- W chunk into registers (rotated i-quad order), verbatim R0 ----
    v2f wr2[64];
    {
        const int jcol0 = jb * 32 + jg * 4;
        #pragma unroll
        for (int k = 0; k < 8; ++k) {
            const int iq = (k + ig) & 7;
            #pragma unroll
            for (int di = 0; di < 4; ++di) {
                const int i = ig * 32 + iq * 4 + di;
                float4 w = *(const float4*)(w_rec + (size_t)i * HH + jcol0);
                const float s = (i < N_EXC) ? 1.0f : -1.0f;
                w.x = (i == jcol0 + 0) ? 0.0f : s * fmaxf(w.x, 0.0f);
                w.y = (i == jcol0 + 1) ? 0.0f : s * fmaxf(w.y, 0.0f);
                w.z = (i == jcol0 + 2) ? 0.0f : s * fmaxf(w.z, 0.0f);
                w.w = (i == jcol0 + 3) ? 0.0f : s * fmaxf(w.w, 0.0f);
                wr2[(k * 4 + di) * 2 + 0] = (v2f){w.x, w.y};
                wr2[(k * 4 + di) * 2 + 1] = (v2f){w.z, w.w};
            }
        }
    }

    const float ax   = (j & 1) ? (20.0f / 200.0f) : (20.0f / 1500.0f);
    const float Uj   = (j & 1) ? 0.15f : 0.45f;
    const float brec = b_rec[j];

    const size_t par  = (size_t)(t & 1) * BB * HH;        // read parity
    const size_t parw = (size_t)((t + 1) & 1) * BB * HH;  // write parity

    #pragma unroll
    for (int p = 0; p < 2; ++p) {
        const int bbase = bb * 16 + p * 8;
        const int b = bbase + sb;

        // --- stage this pass's 8 batches of h_post into LDS (t>0) ---
        if (t > 0) {
            const float4* src = (const float4*)(hp_buf + par + (size_t)bbase * HH);
            float4* dst = (float4*)hp_lds;
            #pragma unroll
            for (int k = 0; k < 8; ++k) dst[tid + k * 256] = src[tid + k * 256];
        }
        const size_t oa = ((size_t)b * TT + t) * HH + j;
        const float d  = acts_drive[oa];
        const float nz = noise[((size_t)t * BB + b) * HH + j];
        __syncthreads();

        // --- FMA: partials over my 32-row i-chunk, 4 cols, 8 batches ---
        if (t > 0) {
            v2f acc[8][2];
            #pragma unroll
            for (int q = 0; q < 8; ++q) { acc[q][0] = (v2f){0.f, 0.f}; acc[q][1] = (v2f){0.f, 0.f}; }
            #pragma unroll
            for (int k = 0; k < 8; ++k) {
                const int iq    = (k + ig) & 7;
                const int ibase = ig * 32 + iq * 4;
                #pragma unroll
                for (int bq = 0; bq < 8; ++bq) {
                    const float4 h4 = *(const float4*)(hp_lds + bq * HH + ibase);
                    const float hv[4] = {h4.x, h4.y, h4.z, h4.w};
                    #pragma unroll
                    for (int di = 0; di < 4; ++di) {
                        const v2f hs = (v2f){hv[di], hv[di]};
                        acc[bq][0] = wr2[(k * 4 + di) * 2 + 0] * hs + acc[bq][0];
                        acc[bq][1] = wr2[(k * 4 + di) * 2 + 1] * hs + acc[bq][1];
                    }
                }
            }
            // --- partials to LDS, skewed by 13*ig (2-way max = free) ---
            const int base = jg * 4 + ig * 13;
            #pragma unroll
            for (int bq = 0; bq < 8; ++bq) {
                float* row = part + ig * 256 + bq * 32;
                row[(base + 0) & 31] = acc[bq][0].x;
                row[(base + 1) & 31] = acc[bq][0].y;
                row[(base + 2) & 31] = acc[bq][1].x;
                row[(base + 3) & 31] = acc[bq][1].y;
            }
        }
        __syncthreads();

        // --- reduce 32 i-group partials at the state-owning thread ---
        float r = 0.0f;
        if (t > 0) {
            #pragma unroll
            for (int g = 0; g < 32; ++g)
                r += part[g * 256 + sb * 32 + ((jj + g * 13) & 31)];
        }

        // --- state load: h(t-1), sx(t), su(t) ---
        float hprev, sxv, suv;
        if (t > 0) {
            hprev = acts_drive[oa - HH];          // acts[b][t-1][j]
            sxv   = sxg[(size_t)b * HH + j];
            suv   = sug[(size_t)b * HH + j];
        } else {
            hprev = 0.0f; sxv = 1.0f; suv = Uj;   // reference t=0 boundary
        }

        // --- neuron update, write act ---
        float v = hprev * (1.0f - ALPHA_N) + ALPHA_N * (d + r + brec)
                  + NOISE_STD * nz;
        const float h = v > 0.0f ? v : 0.0f;
        acts_drive[oa] = h;

        // --- STP update to step t+1; publish h_post(t+1) ---
        float nsx = sxv + ax * (1.0f - sxv) - DT_SEC * suv * sxv * h;
        nsx = fminf(fmaxf(nsx, 0.0f), 1.0f);
        float nsu = suv + ax * (Uj - suv) + DT_SEC * Uj * (1.0f - suv) * h;
        nsu = fminf(fmaxf(nsu, 0.0f), 1.0f);
        sxg[(size_t)b * HH + j] = nsx;
        sug[(size_t)b * HH + j] = nsu;
        hp_buf[parw + (size_t)b * HH + j] = nsu * nsx * h;
        // pass-1 restage of hp_lds is safe (round-0 argument): pass-0 FMA
        // reads finished before pass-0's second __syncthreads; pass-1 part
        // writes are after pass-1's post-staging __syncthreads, hence after
        // all pass-0 reduce reads. hp_buf[parw] writes never alias the
        // hp_buf[par] staging reads (opposite parity).
    }
}

// ---------------- K4: output + classifier projections -----------------
__global__ void proj_kernel(const float* __restrict__ acts, const float* __restrict__ w_out,
                            const float* __restrict__ b_out, const float* __restrict__ c1_w,
                            const float* __restrict__ c1_b, const float* __restrict__ c2_w,
                            const float* __restrict__ c2_b, float* __restrict__ out0,
                            float* __restrict__ outp) {
    int gw   = (int)((blockIdx.x * (size_t)blockDim.x + threadIdx.x) >> 6);
    int lane = threadIdx.x & 63;
    if (gw >= BB * TT) return;
    const float4* arow = (const float4*)(acts + (size_t)gw * HH);
    float accs[9];
    #pragma unroll
    for (int r = 0; r < 9; ++r) accs[r] = 0.f;
    #pragma unroll
    for (int k = 0; k < 4; ++k) {
        int idx = lane + (k << 6);
        float4 a = arow[idx];
        #pragma unroll
        for (int r = 0; r < 9; ++r) {
            const float* wbase = (r < 3) ? (w_out + r * HH) : (c1_w + (size_t)(r - 3) * HH);
            float4 w = ((const float4*)wbase)[idx];
            accs[r] += a.x * w.x + a.y * w.y + a.z * w.z + a.w * w.w;
        }
    }
    #pragma unroll
    for (int r = 0; r < 9; ++r) {
        float v = accs[r];
        #pragma unroll
        for (int off = 32; off > 0; off >>= 1) v += __shfl_down(v, off);
        accs[r] = v;
    }
    if (lane == 0) {
        #pragma unroll
        for (int o = 0; o < 3; ++o) out0[(size_t)gw * 3 + o] = accs[o] + b_out[o];
        float z[6];
        #pragma unroll
        for (int q = 0; q < 6; ++q) z[q] = accs[3 + q] + c1_b[q];
        #pragma unroll
        for (int jc = 0; jc < 3; ++jc) {
            #pragma unroll
            for (int o = 0; o < 8; ++o) {
                float p = c2_b[jc * 8 + o];
                p = fmaf(z[jc * 2 + 0], c2_w[(jc * 8 + o) * 2 + 0], p);
                p = fmaf(z[jc * 2 + 1], c2_w[(jc * 8 + o) * 2 + 1], p);
                outp[(size_t)gw * 24 + jc * 8 + o] = p;
            }
        }
    }
}

extern "C" void kernel_launch(void* const* d_in, const int* in_sizes, int n_in,
                              void* d_out, int out_size, void* d_ws, size_t ws_size,
                              hipStream_t stream) {
    const float* stim  = (const float*)d_in[0];
    const float* ctx   = (const float*)d_in[1];
    const float* w_rec = (const float*)d_in[2];
    const float* b_rec = (const float*)d_in[3];
    const float* w_in  = (const float*)d_in[4];
    const float* w_ctx = (const float*)d_in[5];
    const float* w_out = (const float*)d_in[6];
    const float* b_out = (const float*)d_in[7];
    const float* c1_w  = (const float*)d_in[8];
    const float* c1_b  = (const float*)d_in[9];
    const float* c2_w  = (const float*)d_in[10];
    const float* c2_b  = (const float*)d_in[11];
    const float* noise = (const float*)d_in[12];

    float* out0 = (float*)d_out;                       // [B][T][3]
    float* acts = out0 + (size_t)BB * TT * 3;          // [B][T][H] (drive pre-scan)
    float* outp = acts + (size_t)BB * TT * HH;         // [B][T][3][8]

    float* hp = (float*)d_ws;                          // 2 x 128 x 1024 double buffer
                                                       // (exact round-0 ws layout)
    // sx/su state scratch carved from the outp output region (4.9 MB; needs
    // 1 MB; fully overwritten by proj_kernel afterward). K_0 initializes it
    // itself (t==0 branch), so no memset needed and rocprof replay is safe.
    float* sxg = outp;
    float* sug = outp + (size_t)BB * HH;

    drive_kernel<<<BB * (TT / TCH), 256, 0, stream>>>(stim, ctx, w_in, w_ctx, acts);

    for (int t = 0; t < TT; ++t)
        step_kernel<<<256, 256, 0, stream>>>(w_rec, noise, b_rec, acts,
                                             hp, sxg, sug, t);

    proj_kernel<<<(BB * TT) / 4, 256, 0, stream>>>(acts, w_out, b_out, c1_w, c1_b,
                                                   c2_w, c2_b, out0, outp);
}